// Round 9
// baseline (639.657 us; speedup 1.0000x reference)
//
#include <hip/hip_runtime.h>
#include <hip/hip_cooperative_groups.h>

namespace cg = cooperative_groups;

#define N_NODES 100000
#define N_EDGES 3200000
#define F_IN    128
#define HIDDEN  16
#define F_OUT   2

#define BSZ     256                  // nodes per bucket
#define NB      391                  // ceil(N_NODES / BSZ)
#define NPAD    (NB * BSZ)           // 100096 padded node rows
#define G       512                  // edge partitions (cooperative grid size)
#define EPB     (N_EDGES / G)        // 6250 edges per partition (exact, even)
#define DUMMY_E 100000u              // zeroed pad row used for clamped slots

typedef float  f32x4 __attribute__((ext_vector_type(4)));
typedef float  f32x2 __attribute__((ext_vector_type(2)));
typedef _Float16 half8 __attribute__((ext_vector_type(8)));
typedef _Float16 half4 __attribute__((ext_vector_type(4)));

// ================= cooperative fused sort pipeline =================
// Phases: A local hist+scan+stage (LDS-resident) -> B per-bucket scan over
// partitions -> B2 bucket-total scan -> C grouped placement to adj ->
// D in-bucket counting sort -> adj2/rowstart/dinv.
// bh layout is TRANSPOSED vs fallback: bh[g*NB + i] (coalesced in A and C).
__global__ __launch_bounds__(256, 2) void k_sortall(
    const int* __restrict__ src, const int* __restrict__ dst,
    unsigned* __restrict__ bh,         // [G][NB]
    unsigned* __restrict__ total,      // [NB]
    unsigned* __restrict__ bucketBase, // [NB+1]
    unsigned* __restrict__ adj,
    unsigned* __restrict__ adj2,
    int* __restrict__ rowstart,
    float* __restrict__ dinv)
{
    __shared__ unsigned stage[EPB];            // 25.0 KB
    __shared__ unsigned short stage_b[EPB];    // 12.5 KB
    __shared__ unsigned h0[NB];
    __shared__ unsigned h1[NB];
    __shared__ unsigned lstart[NB];
    __shared__ unsigned gbase[NB];
    __shared__ unsigned ssum[256];
    cg::grid_group grid = cg::this_grid();
    int t = threadIdx.x, g = blockIdx.x;

    // ---------- phase A: local hist + scan + stage ----------
    for (int i = t; i < NB; i += 256) { h0[i] = 0u; h1[i] = 0u; }
    __syncthreads();
    const int2* s2 = (const int2*)(src + g * EPB);
    const int2* d2 = (const int2*)(dst + g * EPB);
    unsigned* myh = (t & 1) ? h1 : h0;
    for (int i = t; i < EPB / 2; i += 256) {
        int2 v = d2[i];
        atomicAdd(&myh[(unsigned)v.x >> 8], 1u);
        atomicAdd(&myh[(unsigned)v.y >> 8], 1u);
    }
    __syncthreads();
    int i0 = t * 2;
    unsigned v0 = (i0 + 0 < NB) ? h0[i0 + 0] + h1[i0 + 0] : 0u;
    unsigned v1 = (i0 + 1 < NB) ? h0[i0 + 1] + h1[i0 + 1] : 0u;
    unsigned my = v0 + v1;
    ssum[t] = my;
    __syncthreads();
    for (int off = 1; off < 256; off <<= 1) {
        unsigned xv = (t >= off) ? ssum[t - off] : 0u;
        __syncthreads();
        ssum[t] += xv;
        __syncthreads();
    }
    unsigned e0 = ssum[t] - my;
    __syncthreads();
    unsigned e1 = e0 + v0;
    if (i0 + 0 < NB) { lstart[i0 + 0] = e0; h0[i0 + 0] = e0; bh[(size_t)g * NB + i0 + 0] = v0; }
    if (i0 + 1 < NB) { lstart[i0 + 1] = e1; h0[i0 + 1] = e1; bh[(size_t)g * NB + i0 + 1] = v1; }
    __syncthreads();
    for (int i = t; i < EPB / 2; i += 256) {   // re-read (L2-hot) + stage
        int2 sv = s2[i], dv = d2[i];
        unsigned b0 = (unsigned)dv.x >> 8;
        unsigned p0 = atomicAdd(&h0[b0], 1u);
        stage[p0] = ((unsigned)(dv.x & 255) << 17) | (unsigned)sv.x;
        stage_b[p0] = (unsigned short)b0;
        unsigned b1 = (unsigned)dv.y >> 8;
        unsigned p1 = atomicAdd(&h0[b1], 1u);
        stage[p1] = ((unsigned)(dv.y & 255) << 17) | (unsigned)sv.y;
        stage_b[p1] = (unsigned short)b1;
    }
    __threadfence(); grid.sync(); __threadfence();

    // ---------- phase B: per-bucket exclusive scan over partitions ----------
    if (g < NB) {
        unsigned w0 = bh[(size_t)(2 * t + 0) * NB + g];
        unsigned w1 = bh[(size_t)(2 * t + 1) * NB + g];
        unsigned s = w0 + w1;
        ssum[t] = s;
        __syncthreads();
        for (int off = 1; off < 256; off <<= 1) {
            unsigned xv = (t >= off) ? ssum[t - off] : 0u;
            __syncthreads();
            ssum[t] += xv;
            __syncthreads();
        }
        unsigned incl = ssum[t], excl = incl - s;
        bh[(size_t)(2 * t + 0) * NB + g] = excl;
        bh[(size_t)(2 * t + 1) * NB + g] = excl + w0;
        if (t == 255) total[g] = incl;
    }
    __threadfence(); grid.sync(); __threadfence();

    // ---------- phase B2: bucket-total scan (block 0) ----------
    if (g == 0) {
        unsigned w0 = (2 * t + 0 < NB) ? total[2 * t + 0] : 0u;
        unsigned w1 = (2 * t + 1 < NB) ? total[2 * t + 1] : 0u;
        unsigned s = w0 + w1;
        ssum[t] = s;
        __syncthreads();
        for (int off = 1; off < 256; off <<= 1) {
            unsigned xv = (t >= off) ? ssum[t - off] : 0u;
            __syncthreads();
            ssum[t] += xv;
            __syncthreads();
        }
        unsigned incl = ssum[t], excl = incl - s;
        if (2 * t + 0 < NB) bucketBase[2 * t + 0] = excl;
        if (2 * t + 1 < NB) bucketBase[2 * t + 1] = excl + w0;
        if (t == 255) { bucketBase[NB] = incl; rowstart[N_NODES] = (int)incl; }
    }
    __threadfence(); grid.sync(); __threadfence();

    // ---------- phase C: grouped placement (stage/lstart still in LDS) ----------
    for (int i = t; i < NB; i += 256) gbase[i] = bucketBase[i] + bh[(size_t)g * NB + i];
    __syncthreads();
    for (int j = t; j < EPB; j += 256) {
        unsigned bkt = stage_b[j];
        adj[gbase[bkt] + (j - lstart[bkt])] = stage[j];
    }
    __threadfence(); grid.sync(); __threadfence();

    // ---------- phase D: in-bucket counting sort -> CSR ----------
    if (g < NB) {
        unsigned* hist = h0; unsigned* sc = h1; unsigned* cur = lstart;  // reuse LDS
        hist[t] = 0u;
        __syncthreads();
        int e0i = (int)bucketBase[g], e1i = (int)bucketBase[g + 1];
        for (int i = e0i + t; i < e1i; i += 256) atomicAdd(&hist[adj[i] >> 17], 1u);
        __syncthreads();
        sc[t] = hist[t];
        __syncthreads();
        for (int off = 1; off < BSZ; off <<= 1) {
            unsigned a = (t >= off) ? sc[t - off] : 0u;
            __syncthreads();
            sc[t] += a;
            __syncthreads();
        }
        unsigned excl = sc[t] - hist[t];
        cur[t] = (unsigned)e0i + excl;
        int node = g * BSZ + t;
        if (node < N_NODES) {
            rowstart[node] = e0i + (int)excl;
            dinv[node] = rsqrtf((float)(hist[t] + 1u));
        }
        __syncthreads();
        for (int i = e0i + t; i < e1i; i += 256) {
            unsigned v = adj[i];
            unsigned pos = atomicAdd(&cur[v >> 17], 1u);
            adj2[pos] = v & 0x1FFFFu;
        }
    }
}

// ================= fallback (non-cooperative) sort pipeline =================
// bh layout here: [i][g] (original). Self-consistent, proven in round 8.
__global__ __launch_bounds__(256) void k_hist(const int* __restrict__ dst,
                                              unsigned* __restrict__ blockHist) {
    __shared__ unsigned h0[NB];
    __shared__ unsigned h1[NB];
    int t = threadIdx.x, g = blockIdx.x;
    for (int i = t; i < NB; i += 256) { h0[i] = 0u; h1[i] = 0u; }
    __syncthreads();
    const int2* d2 = (const int2*)(dst + g * EPB);
    unsigned* myh = (t & 1) ? h1 : h0;
    for (int i = t; i < EPB / 2; i += 256) {
        int2 v = d2[i];
        atomicAdd(&myh[(unsigned)v.x >> 8], 1u);
        atomicAdd(&myh[(unsigned)v.y >> 8], 1u);
    }
    __syncthreads();
    for (int i = t; i < NB; i += 256) blockHist[i * G + g] = h0[i] + h1[i];
}

__global__ __launch_bounds__(G) void k_scan_blocks(unsigned* __restrict__ blockHist,
                                                   unsigned* __restrict__ total) {
    __shared__ unsigned s[G];
    int b = blockIdx.x, t = threadIdx.x;
    unsigned v = blockHist[b * G + t];
    s[t] = v;
    __syncthreads();
    for (int off = 1; off < G; off <<= 1) {
        unsigned xv = (t >= off) ? s[t - off] : 0u;
        __syncthreads();
        s[t] += xv;
        __syncthreads();
    }
    blockHist[b * G + t] = s[t] - v;
    if (t == G - 1) total[b] = s[t];
}

__global__ __launch_bounds__(512) void k_scan_buckets(const unsigned* __restrict__ total,
                                                      unsigned* __restrict__ bucketBase,
                                                      int* __restrict__ rowstart) {
    __shared__ unsigned s[512];
    int t = threadIdx.x;
    unsigned v = (t < NB) ? total[t] : 0u;
    s[t] = v;
    __syncthreads();
    for (int off = 1; off < 512; off <<= 1) {
        unsigned xv = (t >= off) ? s[t - off] : 0u;
        __syncthreads();
        s[t] += xv;
        __syncthreads();
    }
    if (t < NB) bucketBase[t] = s[t] - v;
    if (t == 511) {
        bucketBase[NB] = s[t];
        rowstart[N_NODES] = (int)s[t];
    }
}

__global__ __launch_bounds__(256) void k_scatter(const int* __restrict__ src,
                                                 const int* __restrict__ dst,
                                                 const unsigned* __restrict__ blockHist,
                                                 const unsigned* __restrict__ bucketBase,
                                                 unsigned* __restrict__ adj) {
    __shared__ unsigned stage[EPB];
    __shared__ unsigned short stage_b[EPB];
    __shared__ unsigned hist[NB];
    __shared__ unsigned h1[NB];
    __shared__ unsigned lstart[NB];
    __shared__ unsigned gbase[NB];
    __shared__ unsigned ssum[256];
    int t = threadIdx.x, g = blockIdx.x;
    for (int i = t; i < NB; i += 256) {
        hist[i] = 0u; h1[i] = 0u;
        gbase[i] = bucketBase[i] + blockHist[i * G + g];
    }
    __syncthreads();
    const int2* s2 = (const int2*)(src + g * EPB);
    const int2* d2 = (const int2*)(dst + g * EPB);
    unsigned* myh = (t & 1) ? h1 : hist;
    for (int i = t; i < EPB / 2; i += 256) {
        int2 v = d2[i];
        atomicAdd(&myh[(unsigned)v.x >> 8], 1u);
        atomicAdd(&myh[(unsigned)v.y >> 8], 1u);
    }
    __syncthreads();
    int i0 = t * 2;
    unsigned v0 = (i0 + 0 < NB) ? hist[i0 + 0] + h1[i0 + 0] : 0u;
    unsigned v1 = (i0 + 1 < NB) ? hist[i0 + 1] + h1[i0 + 1] : 0u;
    unsigned my = v0 + v1;
    ssum[t] = my;
    __syncthreads();
    for (int off = 1; off < 256; off <<= 1) {
        unsigned xv = (t >= off) ? ssum[t - off] : 0u;
        __syncthreads();
        ssum[t] += xv;
        __syncthreads();
    }
    unsigned e0 = ssum[t] - my;
    __syncthreads();
    unsigned e1 = e0 + v0;
    if (i0 + 0 < NB) { lstart[i0 + 0] = e0; hist[i0 + 0] = e0; }
    if (i0 + 1 < NB) { lstart[i0 + 1] = e1; hist[i0 + 1] = e1; }
    __syncthreads();
    for (int i = t; i < EPB / 2; i += 256) {
        int2 sv = s2[i], dv = d2[i];
        unsigned bkt0 = (unsigned)dv.x >> 8;
        unsigned pos0 = atomicAdd(&hist[bkt0], 1u);
        stage[pos0] = ((unsigned)(dv.x & 255) << 17) | (unsigned)sv.x;
        stage_b[pos0] = (unsigned short)bkt0;
        unsigned bkt1 = (unsigned)dv.y >> 8;
        unsigned pos1 = atomicAdd(&hist[bkt1], 1u);
        stage[pos1] = ((unsigned)(dv.y & 255) << 17) | (unsigned)sv.y;
        stage_b[pos1] = (unsigned short)bkt1;
    }
    __syncthreads();
    for (int j = t; j < EPB; j += 256) {
        unsigned bkt = stage_b[j];
        adj[gbase[bkt] + (j - lstart[bkt])] = stage[j];
    }
}

__global__ __launch_bounds__(256) void k_sortbucket(const unsigned* __restrict__ adj,
                                                    const unsigned* __restrict__ bucketBase,
                                                    unsigned* __restrict__ adj2,
                                                    int* __restrict__ rowstart,
                                                    float* __restrict__ dinv) {
    __shared__ unsigned hist[BSZ];
    __shared__ unsigned sc[BSZ];
    __shared__ unsigned cur[BSZ];
    int b = blockIdx.x, t = threadIdx.x;
    hist[t] = 0u;
    __syncthreads();
    int e0 = (int)bucketBase[b], e1 = (int)bucketBase[b + 1];
    for (int i = e0 + t; i < e1; i += 256) atomicAdd(&hist[adj[i] >> 17], 1u);
    __syncthreads();
    sc[t] = hist[t];
    __syncthreads();
    for (int off = 1; off < BSZ; off <<= 1) {
        unsigned a = (t >= off) ? sc[t - off] : 0u;
        __syncthreads();
        sc[t] += a;
        __syncthreads();
    }
    unsigned excl = sc[t] - hist[t];
    cur[t] = (unsigned)e0 + excl;
    int node = b * BSZ + t;
    if (node < N_NODES) {
        rowstart[node] = e0 + (int)excl;
        dinv[node] = rsqrtf((float)(hist[t] + 1u));
    }
    __syncthreads();
    for (int i = e0 + t; i < e1; i += 256) {
        unsigned v = adj[i];
        unsigned pos = atomicAdd(&cur[v >> 17], 1u);
        adj2[pos] = v & 0x1FFFFu;
    }
}

// ---------- layer-1 GEMM: hs(fp16) = (x @ W1) * dinv ----------
#define MM1_NODES 64
#define SXP 132
__global__ __launch_bounds__(256) void k_mm1(const float* __restrict__ x,
                                             const float* __restrict__ W1,
                                             const float* __restrict__ dinv,
                                             half4* __restrict__ hs) {
    __shared__ float sW[F_IN * HIDDEN];       // 8 KB
    __shared__ float sX[MM1_NODES * SXP];     // 33 KB
    int t = threadIdx.x;
    for (int i = t; i < F_IN * HIDDEN; i += 256) sW[i] = W1[i];
    int node0 = blockIdx.x * MM1_NODES;
    const float4* xv = (const float4*)(x + (size_t)node0 * F_IN);
    int maxv = (N_NODES - node0) * (F_IN / 4);
    if (maxv < 0) maxv = 0;
    for (int i = t; i < MM1_NODES * (F_IN / 4); i += 256) {
        if (i < maxv) {
            int nl = i >> 5, f4 = i & 31;
            ((float4*)(sX + nl * SXP))[f4] = xv[i];
        }
    }
    __syncthreads();
    int lane4 = t & 3;
    int nl = t >> 2;
    int n = node0 + nl;
    if (n >= NPAD) return;
    if (n >= N_NODES) {                       // zero pad rows incl. DUMMY row
        half4 hz = {(_Float16)0.f, (_Float16)0.f, (_Float16)0.f, (_Float16)0.f};
        hs[(size_t)n * 4 + lane4] = hz;
        return;
    }
    const float4* sWv = (const float4*)sW;
    float4 a = {0.f, 0.f, 0.f, 0.f};
    #pragma unroll 8
    for (int f = 0; f < F_IN; ++f) {
        float xval = sX[nl * SXP + f];
        float4 w = sWv[f * 4 + lane4];
        a.x = fmaf(xval, w.x, a.x);
        a.y = fmaf(xval, w.y, a.y);
        a.z = fmaf(xval, w.z, a.z);
        a.w = fmaf(xval, w.w, a.w);
    }
    float dv = dinv[n];
    half4 h; h[0] = (_Float16)(a.x * dv); h[1] = (_Float16)(a.y * dv);
    h[2] = (_Float16)(a.z * dv); h[3] = (_Float16)(a.w * dv);
    hs[(size_t)n * 4 + lane4] = h;
}

// ---------- layer-1 aggregation + FUSED layer-2 matmul ----------
__global__ __launch_bounds__(256) void k_agg1(const unsigned* __restrict__ adj2,
                                              const int* __restrict__ rowstart,
                                              const char* __restrict__ hs,
                                              const float* __restrict__ dinv,
                                              const float* __restrict__ b1,
                                              const float* __restrict__ W2,
                                              float2* __restrict__ hs2) {
    int g = blockIdx.x * 256 + threadIdx.x;
    int node = g >> 1, le = g & 1;
    if (node >= N_NODES) {
        if (le == 0 && node < NPAD) { float2 z = {0.f, 0.f}; hs2[node] = z; }
        return;
    }
    int rs = rowstart[node], re = rowstart[node + 1];
    unsigned le16 = (unsigned)le * 16u;
    unsigned dummy_off = DUMMY_E * 32u + le16;

    float a0 = 0.f, a1 = 0.f, a2 = 0.f, a3 = 0.f, a4 = 0.f, a5 = 0.f, a6 = 0.f, a7 = 0.f;
    f32x4 w0, w1, w2, w3, w4, w5, w6, w7;

#define GL1(dst, o) asm volatile("global_load_dwordx4 %0, %1, %2" \
    : "=v"(dst) : "v"(o), "s"(hs) : "memory");
#define AC1(w_) { half8 h8; __builtin_memcpy(&h8, &w_, 16); \
    a0 += (float)h8[0]; a1 += (float)h8[1]; a2 += (float)h8[2]; a3 += (float)h8[3]; \
    a4 += (float)h8[4]; a5 += (float)h8[5]; a6 += (float)h8[6]; a7 += (float)h8[7]; }

    for (int bs = rs; bs < re; bs += 8) {
        const unsigned* ap = adj2 + bs;        // adj2 padded by 8 -> safe reads
        unsigned j0 = ap[0], j1 = ap[1], j2 = ap[2], j3 = ap[3];
        unsigned j4 = ap[4], j5 = ap[5], j6 = ap[6], j7 = ap[7];
        unsigned o0 = (bs + 0 < re) ? (j0 << 5) + le16 : dummy_off;
        unsigned o1 = (bs + 1 < re) ? (j1 << 5) + le16 : dummy_off;
        unsigned o2 = (bs + 2 < re) ? (j2 << 5) + le16 : dummy_off;
        unsigned o3 = (bs + 3 < re) ? (j3 << 5) + le16 : dummy_off;
        unsigned o4 = (bs + 4 < re) ? (j4 << 5) + le16 : dummy_off;
        unsigned o5 = (bs + 5 < re) ? (j5 << 5) + le16 : dummy_off;
        unsigned o6 = (bs + 6 < re) ? (j6 << 5) + le16 : dummy_off;
        unsigned o7 = (bs + 7 < re) ? (j7 << 5) + le16 : dummy_off;
        GL1(w0, o0) GL1(w1, o1) GL1(w2, o2) GL1(w3, o3)
        GL1(w4, o4) GL1(w5, o5) GL1(w6, o6) GL1(w7, o7)
        asm volatile("s_waitcnt vmcnt(0)" ::: "memory");
        __builtin_amdgcn_sched_barrier(0);
        AC1(w0) AC1(w1) AC1(w2) AC1(w3) AC1(w4) AC1(w5) AC1(w6) AC1(w7)
    }
    const _Float16* selfrow = (const _Float16*)(hs + (size_t)node * 32 + le16);
    float dv = dinv[node];
    float q0 = dv * (a0 + (float)selfrow[0]), q1 = dv * (a1 + (float)selfrow[1]);
    float q2 = dv * (a2 + (float)selfrow[2]), q3 = dv * (a3 + (float)selfrow[3]);
    float q4 = dv * (a4 + (float)selfrow[4]), q5 = dv * (a5 + (float)selfrow[5]);
    float q6 = dv * (a6 + (float)selfrow[6]), q7 = dv * (a7 + (float)selfrow[7]);
    const float4* b1v = (const float4*)(b1 + le * 8);
    float4 ba = b1v[0], bb = b1v[1];
    const float4* w2v = (const float4*)(W2 + le * 16);
    float4 wA = w2v[0], wB = w2v[1], wC = w2v[2], wD = w2v[3];
    float p0 = 0.f, p1 = 0.f, r;
    r = fmaxf(q0 + ba.x, 0.f); p0 = fmaf(r, wA.x, p0); p1 = fmaf(r, wA.y, p1);
    r = fmaxf(q1 + ba.y, 0.f); p0 = fmaf(r, wA.z, p0); p1 = fmaf(r, wA.w, p1);
    r = fmaxf(q2 + ba.z, 0.f); p0 = fmaf(r, wB.x, p0); p1 = fmaf(r, wB.y, p1);
    r = fmaxf(q3 + ba.w, 0.f); p0 = fmaf(r, wB.z, p0); p1 = fmaf(r, wB.w, p1);
    r = fmaxf(q4 + bb.x, 0.f); p0 = fmaf(r, wC.x, p0); p1 = fmaf(r, wC.y, p1);
    r = fmaxf(q5 + bb.y, 0.f); p0 = fmaf(r, wC.z, p0); p1 = fmaf(r, wC.w, p1);
    r = fmaxf(q6 + bb.z, 0.f); p0 = fmaf(r, wD.x, p0); p1 = fmaf(r, wD.y, p1);
    r = fmaxf(q7 + bb.w, 0.f); p0 = fmaf(r, wD.z, p0); p1 = fmaf(r, wD.w, p1);
    p0 += __shfl_xor(p0, 1);
    p1 += __shfl_xor(p1, 1);
    if (le == 0) {
        float2 h2; h2.x = p0 * dv; h2.y = p1 * dv;
        hs2[node] = h2;
    }
}

// ---------- layer-2 aggregation + finalize ----------
__global__ __launch_bounds__(256) void k_agg2(const unsigned* __restrict__ adj2,
                                              const int* __restrict__ rowstart,
                                              const char* __restrict__ hs2,
                                              const float* __restrict__ dinv,
                                              const float* __restrict__ b2,
                                              float2* __restrict__ out) {
    int node = blockIdx.x * 256 + threadIdx.x;
    if (node >= N_NODES) return;
    int rs = rowstart[node], re = rowstart[node + 1];
    unsigned dummy_off = DUMMY_E * 8u;

    float a0 = 0.f, a1 = 0.f;
    f32x2 w0, w1, w2, w3, w4, w5, w6, w7;

#define GL2(dst, o) asm volatile("global_load_dwordx2 %0, %1, %2" \
    : "=v"(dst) : "v"(o), "s"(hs2) : "memory");

    for (int bs = rs; bs < re; bs += 8) {
        const unsigned* ap = adj2 + bs;
        unsigned j0 = ap[0], j1 = ap[1], j2 = ap[2], j3 = ap[3];
        unsigned j4 = ap[4], j5 = ap[5], j6 = ap[6], j7 = ap[7];
        unsigned o0 = (bs + 0 < re) ? (j0 << 3) : dummy_off;
        unsigned o1 = (bs + 1 < re) ? (j1 << 3) : dummy_off;
        unsigned o2 = (bs + 2 < re) ? (j2 << 3) : dummy_off;
        unsigned o3 = (bs + 3 < re) ? (j3 << 3) : dummy_off;
        unsigned o4 = (bs + 4 < re) ? (j4 << 3) : dummy_off;
        unsigned o5 = (bs + 5 < re) ? (j5 << 3) : dummy_off;
        unsigned o6 = (bs + 6 < re) ? (j6 << 3) : dummy_off;
        unsigned o7 = (bs + 7 < re) ? (j7 << 3) : dummy_off;
        GL2(w0, o0) GL2(w1, o1) GL2(w2, o2) GL2(w3, o3)
        GL2(w4, o4) GL2(w5, o5) GL2(w6, o6) GL2(w7, o7)
        asm volatile("s_waitcnt vmcnt(0)" ::: "memory");
        __builtin_amdgcn_sched_barrier(0);
        a0 += w0[0] + w1[0] + w2[0] + w3[0] + w4[0] + w5[0] + w6[0] + w7[0];
        a1 += w0[1] + w1[1] + w2[1] + w3[1] + w4[1] + w5[1] + w6[1] + w7[1];
    }
    const float2* h2p = (const float2*)hs2;
    float2 selfv = h2p[node];
    float dv = dinv[node];
    float2 r;
    r.x = fmaf(dv, a0 + selfv.x, b2[0]);
    r.y = fmaf(dv, a1 + selfv.y, b2[1]);
    out[node] = r;
}

// ---------- launcher ----------
extern "C" void kernel_launch(void* const* d_in, const int* in_sizes, int n_in,
                              void* d_out, int out_size, void* d_ws, size_t ws_size,
                              hipStream_t stream) {
    const float* x   = (const float*)d_in[0];
    const int*   ei  = (const int*)d_in[1];
    const int*   srcv = ei;
    const int*   dstv = ei + N_EDGES;
    const float* W1  = (const float*)d_in[2];
    const float* b1  = (const float*)d_in[3];
    const float* W2  = (const float*)d_in[4];
    const float* b2  = (const float*)d_in[5];
    float* out = (float*)d_out;

    char* w = (char*)d_ws;
    unsigned* adj        = (unsigned*)w;  w += (size_t)N_EDGES * 4;        // 12.8 MB
    unsigned* adj2       = (unsigned*)w;  w += (size_t)(N_EDGES + 8) * 4;  // 12.8 MB + pad
    unsigned* bh         = (unsigned*)w;  w += (size_t)NB * G * 4;         // 0.8 MB
    unsigned* total      = (unsigned*)w;  w += (size_t)NB * 4;
    unsigned* bucketBase = (unsigned*)w;  w += (size_t)(NB + 1) * 4;
    int*      rowstart   = (int*)w;       w += (size_t)(N_NODES + 1) * 4;  // 0.4 MB
    w = (char*)(((size_t)w + 15) & ~(size_t)15);
    float* dinv  = (float*)w;  w += (size_t)N_NODES * 4;                   // 0.4 MB
    char*  hs    = w;          w += (size_t)NPAD * HIDDEN * 2;             // 3.2 MB fp16
    float* hs2   = (float*)w;                                              // 0.8 MB

    // cooperative fused sort pipeline; fall back to 5-kernel path on error
    void* args[] = { (void*)&srcv, (void*)&dstv, (void*)&bh, (void*)&total,
                     (void*)&bucketBase, (void*)&adj, (void*)&adj2,
                     (void*)&rowstart, (void*)&dinv };
    hipError_t ce = hipLaunchCooperativeKernel((const void*)k_sortall,
                                               dim3(G), dim3(256), args, 0, stream);
    if (ce != hipSuccess) {
        (void)hipGetLastError();   // clear
        k_hist        <<<G, 256, 0, stream>>>(dstv, bh);
        k_scan_blocks <<<NB, G, 0, stream>>>(bh, total);
        k_scan_buckets<<<1, 512, 0, stream>>>(total, bucketBase, rowstart);
        k_scatter     <<<G, 256, 0, stream>>>(srcv, dstv, bh, bucketBase, adj);
        k_sortbucket  <<<NB, 256, 0, stream>>>(adj, bucketBase, adj2, rowstart, dinv);
    }

    k_mm1  <<<NPAD / MM1_NODES, 256, 0, stream>>>(x, W1, dinv, (half4*)hs);
    k_agg1 <<<(2 * NPAD) / 256, 256, 0, stream>>>(adj2, rowstart, hs, dinv,
                                                  b1, W2, (float2*)hs2);
    k_agg2 <<<(NPAD + 255) / 256, 256, 0, stream>>>(adj2, rowstart, (const char*)hs2,
                                                    dinv, b2, (float2*)out);
}

// Round 10
// 146.467 us; speedup vs baseline: 4.3672x; 4.3672x over previous
//
#include <hip/hip_runtime.h>

#define N_NODES 100000
#define N_EDGES 3200000
#define F_IN    128
#define HIDDEN  16
#define F_OUT   2

#define BSZ     256                  // nodes per bucket
#define NB      391                  // ceil(N_NODES / BSZ)
#define NPAD    (NB * BSZ)           // 100096 padded node rows
#define G       512                  // edge partitions for scatter
#define EPB     (N_EDGES / G)        // 6250 edges per partition (exact, even)
#define CAP     9216                 // per-bucket slack capacity (mean 8192 + 11 sigma)
#define DUMMY_E 100000u              // zeroed pad row used for clamped slots

typedef float  f32x4 __attribute__((ext_vector_type(4)));
typedef float  f32x2 __attribute__((ext_vector_type(2)));
typedef _Float16 half8 __attribute__((ext_vector_type(8)));
typedef _Float16 half4 __attribute__((ext_vector_type(4)));

// ---------- P0: zero the bucket cursors (must re-zero every call) ----------
__global__ __launch_bounds__(512) void k_init(unsigned* __restrict__ cursor) {
    int t = threadIdx.x;
    if (t < NB) cursor[t] = 0u;
}

// ---------- P1: LDS counting-sort scatter with atomic bucket reservation ----------
// entry: (dst & 255) << 17 | src ; dest: adj[bkt*CAP + reserved + local_rank]
__global__ __launch_bounds__(256) void k_scatter(const int* __restrict__ src,
                                                 const int* __restrict__ dst,
                                                 unsigned* __restrict__ cursor,
                                                 unsigned* __restrict__ adj) {
    __shared__ unsigned stage[EPB];            // 25.0 KB packed, bucket-ordered
    __shared__ unsigned short stage_b[EPB];    // 12.5 KB bucket id
    __shared__ unsigned h0[NB];                // hist -> local cursor
    __shared__ unsigned h1[NB];                // sub-hist
    __shared__ unsigned lstart[NB];            // local exclusive scan
    __shared__ unsigned gbase[NB];             // atomically reserved global base
    __shared__ unsigned ssum[256];
    int t = threadIdx.x, g = blockIdx.x;
    for (int i = t; i < NB; i += 256) { h0[i] = 0u; h1[i] = 0u; }
    __syncthreads();
    const int2* s2 = (const int2*)(src + g * EPB);
    const int2* d2 = (const int2*)(dst + g * EPB);
    // phase 1: local histogram (2 sub-hists to halve same-bin contention)
    unsigned* myh = (t & 1) ? h1 : h0;
    for (int i = t; i < EPB / 2; i += 256) {
        int2 v = d2[i];
        atomicAdd(&myh[(unsigned)v.x >> 8], 1u);
        atomicAdd(&myh[(unsigned)v.y >> 8], 1u);
    }
    __syncthreads();
    // phase 2: merge + local exclusive scan -> lstart; h0 becomes staging cursor;
    //          atomic reserve of [gbase, gbase+cnt) per bucket in global adj.
    int i0 = t * 2;
    unsigned v0 = (i0 + 0 < NB) ? h0[i0 + 0] + h1[i0 + 0] : 0u;
    unsigned v1 = (i0 + 1 < NB) ? h0[i0 + 1] + h1[i0 + 1] : 0u;
    unsigned my = v0 + v1;
    ssum[t] = my;
    __syncthreads();
    for (int off = 1; off < 256; off <<= 1) {
        unsigned xv = (t >= off) ? ssum[t - off] : 0u;
        __syncthreads();
        ssum[t] += xv;
        __syncthreads();
    }
    unsigned e0 = ssum[t] - my;
    __syncthreads();
    unsigned e1 = e0 + v0;
    if (i0 + 0 < NB) {
        lstart[i0 + 0] = e0; h0[i0 + 0] = e0;
        gbase[i0 + 0] = atomicAdd(&cursor[i0 + 0], v0);
    }
    if (i0 + 1 < NB) {
        lstart[i0 + 1] = e1; h0[i0 + 1] = e1;
        gbase[i0 + 1] = atomicAdd(&cursor[i0 + 1], v1);
    }
    __syncthreads();
    // phase 3: stage entries bucket-ordered in LDS
    for (int i = t; i < EPB / 2; i += 256) {
        int2 sv = s2[i], dv = d2[i];
        unsigned b0 = (unsigned)dv.x >> 8;
        unsigned p0 = atomicAdd(&h0[b0], 1u);
        stage[p0] = ((unsigned)(dv.x & 255) << 17) | (unsigned)sv.x;
        stage_b[p0] = (unsigned short)b0;
        unsigned b1 = (unsigned)dv.y >> 8;
        unsigned p1 = atomicAdd(&h0[b1], 1u);
        stage[p1] = ((unsigned)(dv.y & 255) << 17) | (unsigned)sv.y;
        stage_b[p1] = (unsigned short)b1;
    }
    __syncthreads();
    // phase 4: grouped global writes (runs of ~16 = full 64B lines)
    for (int j = t; j < EPB; j += 256) {
        unsigned bkt = stage_b[j];
        adj[(unsigned)bkt * CAP + gbase[bkt] + (j - lstart[bkt])] = stage[j];
    }
}

// ---------- P2: in-bucket counting sort -> CSR (adj2, rs/re absolute), dinv ----------
__global__ __launch_bounds__(256) void k_sortbucket(const unsigned* __restrict__ adj,
                                                    const unsigned* __restrict__ cursor,
                                                    unsigned* __restrict__ adj2,
                                                    int* __restrict__ rsA,
                                                    int* __restrict__ reA,
                                                    float* __restrict__ dinv) {
    __shared__ unsigned hist[BSZ];
    __shared__ unsigned sc[BSZ];
    __shared__ unsigned cur[BSZ];
    int b = blockIdx.x, t = threadIdx.x;
    hist[t] = 0u;
    __syncthreads();
    int e0 = b * CAP, e1 = e0 + (int)cursor[b];
    for (int i = e0 + t; i < e1; i += 256) atomicAdd(&hist[adj[i] >> 17], 1u);
    __syncthreads();
    sc[t] = hist[t];
    __syncthreads();
    for (int off = 1; off < BSZ; off <<= 1) {
        unsigned a = (t >= off) ? sc[t - off] : 0u;
        __syncthreads();
        sc[t] += a;
        __syncthreads();
    }
    unsigned excl = sc[t] - hist[t];
    cur[t] = (unsigned)e0 + excl;
    int node = b * BSZ + t;
    if (node < N_NODES) {
        rsA[node] = e0 + (int)excl;
        reA[node] = e0 + (int)(excl + hist[t]);
        dinv[node] = rsqrtf((float)(hist[t] + 1u));
    }
    __syncthreads();
    for (int i = e0 + t; i < e1; i += 256) {
        unsigned v = adj[i];
        unsigned pos = atomicAdd(&cur[v >> 17], 1u);
        adj2[pos] = v & 0x1FFFFu;
    }
}

// ---------- layer-1 GEMM: hs(fp16) = (x @ W1) * dinv ----------
#define MM1_NODES 64
#define SXP 132
__global__ __launch_bounds__(256) void k_mm1(const float* __restrict__ x,
                                             const float* __restrict__ W1,
                                             const float* __restrict__ dinv,
                                             half4* __restrict__ hs) {
    __shared__ float sW[F_IN * HIDDEN];       // 8 KB
    __shared__ float sX[MM1_NODES * SXP];     // 33 KB
    int t = threadIdx.x;
    for (int i = t; i < F_IN * HIDDEN; i += 256) sW[i] = W1[i];
    int node0 = blockIdx.x * MM1_NODES;
    const float4* xv = (const float4*)(x + (size_t)node0 * F_IN);
    int maxv = (N_NODES - node0) * (F_IN / 4);
    if (maxv < 0) maxv = 0;
    for (int i = t; i < MM1_NODES * (F_IN / 4); i += 256) {
        if (i < maxv) {
            int nl = i >> 5, f4 = i & 31;
            ((float4*)(sX + nl * SXP))[f4] = xv[i];
        }
    }
    __syncthreads();
    int lane4 = t & 3;
    int nl = t >> 2;
    int n = node0 + nl;
    if (n >= NPAD) return;
    if (n >= N_NODES) {                       // zero pad rows incl. DUMMY row
        half4 hz = {(_Float16)0.f, (_Float16)0.f, (_Float16)0.f, (_Float16)0.f};
        hs[(size_t)n * 4 + lane4] = hz;
        return;
    }
    const float4* sWv = (const float4*)sW;
    float4 a = {0.f, 0.f, 0.f, 0.f};
    #pragma unroll 8
    for (int f = 0; f < F_IN; ++f) {
        float xval = sX[nl * SXP + f];
        float4 w = sWv[f * 4 + lane4];
        a.x = fmaf(xval, w.x, a.x);
        a.y = fmaf(xval, w.y, a.y);
        a.z = fmaf(xval, w.z, a.z);
        a.w = fmaf(xval, w.w, a.w);
    }
    float dv = dinv[n];
    half4 h; h[0] = (_Float16)(a.x * dv); h[1] = (_Float16)(a.y * dv);
    h[2] = (_Float16)(a.z * dv); h[3] = (_Float16)(a.w * dv);
    hs[(size_t)n * 4 + lane4] = h;
}

// ---------- layer-1 aggregation + FUSED layer-2 matmul ----------
// 2 lanes per node; each lane owns 8 fp16 channels; asm-forced 8-deep gathers.
__global__ __launch_bounds__(256) void k_agg1(const unsigned* __restrict__ adj2,
                                              const int* __restrict__ rsA,
                                              const int* __restrict__ reA,
                                              const char* __restrict__ hs,
                                              const float* __restrict__ dinv,
                                              const float* __restrict__ b1,
                                              const float* __restrict__ W2,
                                              float2* __restrict__ hs2) {
    int g = blockIdx.x * 256 + threadIdx.x;
    int node = g >> 1, le = g & 1;
    if (node >= N_NODES) {                     // zero pad rows incl. DUMMY
        if (le == 0 && node < NPAD) { float2 z = {0.f, 0.f}; hs2[node] = z; }
        return;
    }
    int rs0 = rsA[node], re0 = reA[node];
    unsigned le16 = (unsigned)le * 16u;
    unsigned dummy_off = DUMMY_E * 32u + le16;

    float a0 = 0.f, a1 = 0.f, a2 = 0.f, a3 = 0.f, a4 = 0.f, a5 = 0.f, a6 = 0.f, a7 = 0.f;
    f32x4 w0, w1, w2, w3, w4, w5, w6, w7;

#define GL1(dst, o) asm volatile("global_load_dwordx4 %0, %1, %2" \
    : "=v"(dst) : "v"(o), "s"(hs) : "memory");
#define AC1(w_) { half8 h8; __builtin_memcpy(&h8, &w_, 16); \
    a0 += (float)h8[0]; a1 += (float)h8[1]; a2 += (float)h8[2]; a3 += (float)h8[3]; \
    a4 += (float)h8[4]; a5 += (float)h8[5]; a6 += (float)h8[6]; a7 += (float)h8[7]; }

    for (int bs = rs0; bs < re0; bs += 8) {
        const unsigned* ap = adj2 + bs;        // adj2 padded -> safe overreads
        unsigned j0 = ap[0], j1 = ap[1], j2 = ap[2], j3 = ap[3];
        unsigned j4 = ap[4], j5 = ap[5], j6 = ap[6], j7 = ap[7];
        unsigned o0 = (bs + 0 < re0) ? (j0 << 5) + le16 : dummy_off;
        unsigned o1 = (bs + 1 < re0) ? (j1 << 5) + le16 : dummy_off;
        unsigned o2 = (bs + 2 < re0) ? (j2 << 5) + le16 : dummy_off;
        unsigned o3 = (bs + 3 < re0) ? (j3 << 5) + le16 : dummy_off;
        unsigned o4 = (bs + 4 < re0) ? (j4 << 5) + le16 : dummy_off;
        unsigned o5 = (bs + 5 < re0) ? (j5 << 5) + le16 : dummy_off;
        unsigned o6 = (bs + 6 < re0) ? (j6 << 5) + le16 : dummy_off;
        unsigned o7 = (bs + 7 < re0) ? (j7 << 5) + le16 : dummy_off;
        GL1(w0, o0) GL1(w1, o1) GL1(w2, o2) GL1(w3, o3)
        GL1(w4, o4) GL1(w5, o5) GL1(w6, o6) GL1(w7, o7)
        asm volatile("s_waitcnt vmcnt(0)" ::: "memory");
        __builtin_amdgcn_sched_barrier(0);
        AC1(w0) AC1(w1) AC1(w2) AC1(w3) AC1(w4) AC1(w5) AC1(w6) AC1(w7)
    }
    const _Float16* selfrow = (const _Float16*)(hs + (size_t)node * 32 + le16);
    float dv = dinv[node];
    float q0 = dv * (a0 + (float)selfrow[0]), q1 = dv * (a1 + (float)selfrow[1]);
    float q2 = dv * (a2 + (float)selfrow[2]), q3 = dv * (a3 + (float)selfrow[3]);
    float q4 = dv * (a4 + (float)selfrow[4]), q5 = dv * (a5 + (float)selfrow[5]);
    float q6 = dv * (a6 + (float)selfrow[6]), q7 = dv * (a7 + (float)selfrow[7]);
    const float4* b1v = (const float4*)(b1 + le * 8);
    float4 ba = b1v[0], bb = b1v[1];
    const float4* w2v = (const float4*)(W2 + le * 16);
    float4 wA = w2v[0], wB = w2v[1], wC = w2v[2], wD = w2v[3];
    float p0 = 0.f, p1 = 0.f, r;
    r = fmaxf(q0 + ba.x, 0.f); p0 = fmaf(r, wA.x, p0); p1 = fmaf(r, wA.y, p1);
    r = fmaxf(q1 + ba.y, 0.f); p0 = fmaf(r, wA.z, p0); p1 = fmaf(r, wA.w, p1);
    r = fmaxf(q2 + ba.z, 0.f); p0 = fmaf(r, wB.x, p0); p1 = fmaf(r, wB.y, p1);
    r = fmaxf(q3 + ba.w, 0.f); p0 = fmaf(r, wB.z, p0); p1 = fmaf(r, wB.w, p1);
    r = fmaxf(q4 + bb.x, 0.f); p0 = fmaf(r, wC.x, p0); p1 = fmaf(r, wC.y, p1);
    r = fmaxf(q5 + bb.y, 0.f); p0 = fmaf(r, wC.z, p0); p1 = fmaf(r, wC.w, p1);
    r = fmaxf(q6 + bb.z, 0.f); p0 = fmaf(r, wD.x, p0); p1 = fmaf(r, wD.y, p1);
    r = fmaxf(q7 + bb.w, 0.f); p0 = fmaf(r, wD.z, p0); p1 = fmaf(r, wD.w, p1);
    p0 += __shfl_xor(p0, 1);
    p1 += __shfl_xor(p1, 1);
    if (le == 0) {
        float2 h2; h2.x = p0 * dv; h2.y = p1 * dv;
        hs2[node] = h2;
    }
}

// ---------- layer-2 aggregation + finalize ----------
__global__ __launch_bounds__(256) void k_agg2(const unsigned* __restrict__ adj2,
                                              const int* __restrict__ rsA,
                                              const int* __restrict__ reA,
                                              const char* __restrict__ hs2,
                                              const float* __restrict__ dinv,
                                              const float* __restrict__ b2,
                                              float2* __restrict__ out) {
    int node = blockIdx.x * 256 + threadIdx.x;
    if (node >= N_NODES) return;
    int rs0 = rsA[node], re0 = reA[node];
    unsigned dummy_off = DUMMY_E * 8u;

    float a0 = 0.f, a1 = 0.f;
    f32x2 w0, w1, w2, w3, w4, w5, w6, w7;

#define GL2(dst, o) asm volatile("global_load_dwordx2 %0, %1, %2" \
    : "=v"(dst) : "v"(o), "s"(hs2) : "memory");

    for (int bs = rs0; bs < re0; bs += 8) {
        const unsigned* ap = adj2 + bs;
        unsigned j0 = ap[0], j1 = ap[1], j2 = ap[2], j3 = ap[3];
        unsigned j4 = ap[4], j5 = ap[5], j6 = ap[6], j7 = ap[7];
        unsigned o0 = (bs + 0 < re0) ? (j0 << 3) : dummy_off;
        unsigned o1 = (bs + 1 < re0) ? (j1 << 3) : dummy_off;
        unsigned o2 = (bs + 2 < re0) ? (j2 << 3) : dummy_off;
        unsigned o3 = (bs + 3 < re0) ? (j3 << 3) : dummy_off;
        unsigned o4 = (bs + 4 < re0) ? (j4 << 3) : dummy_off;
        unsigned o5 = (bs + 5 < re0) ? (j5 << 3) : dummy_off;
        unsigned o6 = (bs + 6 < re0) ? (j6 << 3) : dummy_off;
        unsigned o7 = (bs + 7 < re0) ? (j7 << 3) : dummy_off;
        GL2(w0, o0) GL2(w1, o1) GL2(w2, o2) GL2(w3, o3)
        GL2(w4, o4) GL2(w5, o5) GL2(w6, o6) GL2(w7, o7)
        asm volatile("s_waitcnt vmcnt(0)" ::: "memory");
        __builtin_amdgcn_sched_barrier(0);
        a0 += w0[0] + w1[0] + w2[0] + w3[0] + w4[0] + w5[0] + w6[0] + w7[0];
        a1 += w0[1] + w1[1] + w2[1] + w3[1] + w4[1] + w5[1] + w6[1] + w7[1];
    }
    const float2* h2p = (const float2*)hs2;
    float2 selfv = h2p[node];
    float dv = dinv[node];
    float2 r;
    r.x = fmaf(dv, a0 + selfv.x, b2[0]);
    r.y = fmaf(dv, a1 + selfv.y, b2[1]);
    out[node] = r;
}

// ---------- launcher ----------
extern "C" void kernel_launch(void* const* d_in, const int* in_sizes, int n_in,
                              void* d_out, int out_size, void* d_ws, size_t ws_size,
                              hipStream_t stream) {
    const float* x   = (const float*)d_in[0];
    const int*   ei  = (const int*)d_in[1];
    const int*   srcv = ei;
    const int*   dstv = ei + N_EDGES;
    const float* W1  = (const float*)d_in[2];
    const float* b1  = (const float*)d_in[3];
    const float* W2  = (const float*)d_in[4];
    const float* b2  = (const float*)d_in[5];
    float* out = (float*)d_out;

    char* w = (char*)d_ws;
    unsigned* adj    = (unsigned*)w;  w += (size_t)NB * CAP * 4;          // 14.4 MB (dead after sortbucket)
    unsigned* adj2   = (unsigned*)w;  w += (size_t)(NB * CAP + 8) * 4;    // 14.4 MB + pad
    unsigned* cursor = (unsigned*)w;  w += (size_t)NB * 4;
    int*      rsA    = (int*)w;       w += (size_t)N_NODES * 4;           // 0.4 MB
    int*      reA    = (int*)w;       w += (size_t)N_NODES * 4;           // 0.4 MB
    float*    dinv   = (float*)w;     w += (size_t)N_NODES * 4;           // 0.4 MB
    // hs / hs2 alias the dead adj region (mm1 runs after sortbucket)
    char*  hs  = (char*)adj;                                              // 3.2 MB fp16
    float* hs2 = (float*)(hs + (size_t)NPAD * HIDDEN * 2);                // 0.8 MB

    k_init       <<<1, 512, 0, stream>>>(cursor);
    k_scatter    <<<G, 256, 0, stream>>>(srcv, dstv, cursor, adj);
    k_sortbucket <<<NB, 256, 0, stream>>>(adj, cursor, adj2, rsA, reA, dinv);
    k_mm1        <<<NPAD / MM1_NODES, 256, 0, stream>>>(x, W1, dinv, (half4*)hs);
    k_agg1       <<<(2 * NPAD) / 256, 256, 0, stream>>>(adj2, rsA, reA, hs, dinv,
                                                        b1, W2, (float2*)hs2);
    k_agg2       <<<(NPAD + 255) / 256, 256, 0, stream>>>(adj2, rsA, reA, (const char*)hs2,
                                                          dinv, b2, (float2*)out);
}

// Round 11
// 145.218 us; speedup vs baseline: 4.4048x; 1.0086x over previous
//
#include <hip/hip_runtime.h>

#define N_NODES 100000
#define N_EDGES 3200000
#define F_IN    128
#define HIDDEN  16
#define F_OUT   2

#define BSZ     256                  // nodes per bucket
#define NB      391                  // ceil(N_NODES / BSZ)
#define NPAD    (NB * BSZ)           // 100096 padded node rows
#define G       800                  // edge partitions for scatter
#define EPB     (N_EDGES / G)        // 4000 edges per partition (exact, even)
#define CAP     9216                 // per-bucket slack capacity (mean 8192 + 11 sigma)
#define DUMMY_E 100000u              // zeroed pad row used for clamped slots

typedef float  f32x4 __attribute__((ext_vector_type(4)));
typedef float  f32x2 __attribute__((ext_vector_type(2)));
typedef _Float16 half8 __attribute__((ext_vector_type(8)));
typedef _Float16 half4 __attribute__((ext_vector_type(4)));

// ---------- P0: zero the bucket cursors (must re-zero every call) ----------
__global__ __launch_bounds__(512) void k_init(unsigned* __restrict__ cursor) {
    int t = threadIdx.x;
    if (t < NB) cursor[t] = 0u;
}

// ---------- P1: LDS counting-sort scatter with staggered atomic reservation ----------
// entry: (dst & 255) << 17 | src ; dest: adj[bkt*CAP + gbase + local_rank]
// LDS ~23.4 KB -> 6 blocks/CU. Bucket id recovered at write time by binary
// search over lstart (no stage_b array).
__global__ __launch_bounds__(256) void k_scatter(const int* __restrict__ src,
                                                 const int* __restrict__ dst,
                                                 unsigned* __restrict__ cursor,
                                                 unsigned* __restrict__ adj) {
    __shared__ unsigned stage[EPB];            // 16.0 KB packed, bucket-ordered
    __shared__ unsigned h0[NB];                // hist -> staging cursor
    __shared__ unsigned h1[NB];                // sub-hist
    __shared__ unsigned lstart[NB + 1];        // local exclusive scan + sentinel
    __shared__ unsigned gbase[NB];             // atomically reserved global base
    __shared__ unsigned ssum[256];
    int t = threadIdx.x, g = blockIdx.x;
    for (int i = t; i < NB; i += 256) { h0[i] = 0u; h1[i] = 0u; }
    __syncthreads();
    const int2* s2 = (const int2*)(src + g * EPB);
    const int2* d2 = (const int2*)(dst + g * EPB);
    // phase 1: local histogram (2 sub-hists to halve same-bin contention)
    unsigned* myh = (t & 1) ? h1 : h0;
    for (int i = t; i < EPB / 2; i += 256) {
        int2 v = d2[i];
        atomicAdd(&myh[(unsigned)v.x >> 8], 1u);
        atomicAdd(&myh[(unsigned)v.y >> 8], 1u);
    }
    __syncthreads();
    // phase 2: merge + local exclusive scan -> lstart; h0 becomes staging cursor
    int i0 = t * 2;
    unsigned v0 = (i0 + 0 < NB) ? h0[i0 + 0] + h1[i0 + 0] : 0u;
    unsigned v1 = (i0 + 1 < NB) ? h0[i0 + 1] + h1[i0 + 1] : 0u;
    unsigned my = v0 + v1;
    ssum[t] = my;
    __syncthreads();
    for (int off = 1; off < 256; off <<= 1) {
        unsigned xv = (t >= off) ? ssum[t - off] : 0u;
        __syncthreads();
        ssum[t] += xv;
        __syncthreads();
    }
    unsigned e0 = ssum[t] - my;
    __syncthreads();                            // all h0/h1 reads done before overwrite
    unsigned e1 = e0 + v0;
    if (i0 + 0 < NB) { lstart[i0 + 0] = e0; h0[i0 + 0] = e0; }
    if (i0 + 1 < NB) { lstart[i0 + 1] = e1; h0[i0 + 1] = e1; }
    if (t == 255) lstart[NB] = EPB;             // sentinel
    __syncthreads();
    // phase 2b: reserve global ranges EARLY (latency hides under staging),
    // rotated so no two blocks hit the same cursor line simultaneously.
    for (int i = t; i < NB; i += 256) {
        int bb = i + (g % NB); if (bb >= NB) bb -= NB;
        unsigned cnt = lstart[bb + 1] - lstart[bb];
        gbase[bb] = atomicAdd(&cursor[bb], cnt);
    }
    // phase 3: stage entries bucket-ordered in LDS (doesn't touch gbase)
    for (int i = t; i < EPB / 2; i += 256) {
        int2 sv = s2[i], dv = d2[i];
        unsigned b0 = (unsigned)dv.x >> 8;
        unsigned p0 = atomicAdd(&h0[b0], 1u);
        stage[p0] = ((unsigned)(dv.x & 255) << 17) | (unsigned)sv.x;
        unsigned b1 = (unsigned)dv.y >> 8;
        unsigned p1 = atomicAdd(&h0[b1], 1u);
        stage[p1] = ((unsigned)(dv.y & 255) << 17) | (unsigned)sv.y;
    }
    __syncthreads();
    // phase 4: grouped global writes; bucket id via binary search in lstart
    for (int j = t; j < EPB; j += 256) {
        int lo = 0, hi = NB;
        while (hi - lo > 1) {
            int mid = (lo + hi) >> 1;
            lo = (lstart[mid] <= (unsigned)j) ? mid : lo;
            hi = (lstart[mid] <= (unsigned)j) ? hi : mid;
        }
        adj[(unsigned)lo * CAP + gbase[lo] + ((unsigned)j - lstart[lo])] = stage[j];
    }
}

// ---------- P2: in-bucket counting sort -> CSR (adj2, rs/re absolute), dinv ----------
__global__ __launch_bounds__(256) void k_sortbucket(const unsigned* __restrict__ adj,
                                                    const unsigned* __restrict__ cursor,
                                                    unsigned* __restrict__ adj2,
                                                    int* __restrict__ rsA,
                                                    int* __restrict__ reA,
                                                    float* __restrict__ dinv) {
    __shared__ unsigned hist[BSZ];
    __shared__ unsigned sc[BSZ];
    __shared__ unsigned cur[BSZ];
    int b = blockIdx.x, t = threadIdx.x;
    hist[t] = 0u;
    __syncthreads();
    int e0 = b * CAP, e1 = e0 + (int)cursor[b];
    for (int i = e0 + t; i < e1; i += 256) atomicAdd(&hist[adj[i] >> 17], 1u);
    __syncthreads();
    sc[t] = hist[t];
    __syncthreads();
    for (int off = 1; off < BSZ; off <<= 1) {
        unsigned a = (t >= off) ? sc[t - off] : 0u;
        __syncthreads();
        sc[t] += a;
        __syncthreads();
    }
    unsigned excl = sc[t] - hist[t];
    cur[t] = (unsigned)e0 + excl;
    int node = b * BSZ + t;
    if (node < N_NODES) {
        rsA[node] = e0 + (int)excl;
        reA[node] = e0 + (int)(excl + hist[t]);
        dinv[node] = rsqrtf((float)(hist[t] + 1u));
    }
    __syncthreads();
    for (int i = e0 + t; i < e1; i += 256) {
        unsigned v = adj[i];
        unsigned pos = atomicAdd(&cur[v >> 17], 1u);
        adj2[pos] = v & 0x1FFFFu;
    }
}

// ---------- layer-1 GEMM: hs(fp16) = (x @ W1) * dinv ----------
#define MM1_NODES 64
#define SXP 132
__global__ __launch_bounds__(256) void k_mm1(const float* __restrict__ x,
                                             const float* __restrict__ W1,
                                             const float* __restrict__ dinv,
                                             half4* __restrict__ hs) {
    __shared__ float sW[F_IN * HIDDEN];       // 8 KB
    __shared__ float sX[MM1_NODES * SXP];     // 33 KB
    int t = threadIdx.x;
    for (int i = t; i < F_IN * HIDDEN; i += 256) sW[i] = W1[i];
    int node0 = blockIdx.x * MM1_NODES;
    const float4* xv = (const float4*)(x + (size_t)node0 * F_IN);
    int maxv = (N_NODES - node0) * (F_IN / 4);
    if (maxv < 0) maxv = 0;
    for (int i = t; i < MM1_NODES * (F_IN / 4); i += 256) {
        if (i < maxv) {
            int nl = i >> 5, f4 = i & 31;
            ((float4*)(sX + nl * SXP))[f4] = xv[i];
        }
    }
    __syncthreads();
    int lane4 = t & 3;
    int nl = t >> 2;
    int n = node0 + nl;
    if (n >= NPAD) return;
    if (n >= N_NODES) {                       // zero pad rows incl. DUMMY row
        half4 hz = {(_Float16)0.f, (_Float16)0.f, (_Float16)0.f, (_Float16)0.f};
        hs[(size_t)n * 4 + lane4] = hz;
        return;
    }
    const float4* sWv = (const float4*)sW;
    float4 a = {0.f, 0.f, 0.f, 0.f};
    #pragma unroll 8
    for (int f = 0; f < F_IN; ++f) {
        float xval = sX[nl * SXP + f];
        float4 w = sWv[f * 4 + lane4];
        a.x = fmaf(xval, w.x, a.x);
        a.y = fmaf(xval, w.y, a.y);
        a.z = fmaf(xval, w.z, a.z);
        a.w = fmaf(xval, w.w, a.w);
    }
    float dv = dinv[n];
    half4 h; h[0] = (_Float16)(a.x * dv); h[1] = (_Float16)(a.y * dv);
    h[2] = (_Float16)(a.z * dv); h[3] = (_Float16)(a.w * dv);
    hs[(size_t)n * 4 + lane4] = h;
}

// ---------- layer-1 aggregation + FUSED layer-2 matmul ----------
// 2 lanes per node; each lane owns 8 fp16 channels; asm-forced 8-deep gathers.
__global__ __launch_bounds__(256) void k_agg1(const unsigned* __restrict__ adj2,
                                              const int* __restrict__ rsA,
                                              const int* __restrict__ reA,
                                              const char* __restrict__ hs,
                                              const float* __restrict__ dinv,
                                              const float* __restrict__ b1,
                                              const float* __restrict__ W2,
                                              float2* __restrict__ hs2) {
    int g = blockIdx.x * 256 + threadIdx.x;
    int node = g >> 1, le = g & 1;
    if (node >= N_NODES) {                     // zero pad rows incl. DUMMY
        if (le == 0 && node < NPAD) { float2 z = {0.f, 0.f}; hs2[node] = z; }
        return;
    }
    int rs0 = rsA[node], re0 = reA[node];
    unsigned le16 = (unsigned)le * 16u;
    unsigned dummy_off = DUMMY_E * 32u + le16;

    float a0 = 0.f, a1 = 0.f, a2 = 0.f, a3 = 0.f, a4 = 0.f, a5 = 0.f, a6 = 0.f, a7 = 0.f;
    f32x4 w0, w1, w2, w3, w4, w5, w6, w7;

#define GL1(dst, o) asm volatile("global_load_dwordx4 %0, %1, %2" \
    : "=v"(dst) : "v"(o), "s"(hs) : "memory");
#define AC1(w_) { half8 h8; __builtin_memcpy(&h8, &w_, 16); \
    a0 += (float)h8[0]; a1 += (float)h8[1]; a2 += (float)h8[2]; a3 += (float)h8[3]; \
    a4 += (float)h8[4]; a5 += (float)h8[5]; a6 += (float)h8[6]; a7 += (float)h8[7]; }

    for (int bs = rs0; bs < re0; bs += 8) {
        const unsigned* ap = adj2 + bs;        // adj2 padded -> safe overreads
        unsigned j0 = ap[0], j1 = ap[1], j2 = ap[2], j3 = ap[3];
        unsigned j4 = ap[4], j5 = ap[5], j6 = ap[6], j7 = ap[7];
        unsigned o0 = (bs + 0 < re0) ? (j0 << 5) + le16 : dummy_off;
        unsigned o1 = (bs + 1 < re0) ? (j1 << 5) + le16 : dummy_off;
        unsigned o2 = (bs + 2 < re0) ? (j2 << 5) + le16 : dummy_off;
        unsigned o3 = (bs + 3 < re0) ? (j3 << 5) + le16 : dummy_off;
        unsigned o4 = (bs + 4 < re0) ? (j4 << 5) + le16 : dummy_off;
        unsigned o5 = (bs + 5 < re0) ? (j5 << 5) + le16 : dummy_off;
        unsigned o6 = (bs + 6 < re0) ? (j6 << 5) + le16 : dummy_off;
        unsigned o7 = (bs + 7 < re0) ? (j7 << 5) + le16 : dummy_off;
        GL1(w0, o0) GL1(w1, o1) GL1(w2, o2) GL1(w3, o3)
        GL1(w4, o4) GL1(w5, o5) GL1(w6, o6) GL1(w7, o7)
        asm volatile("s_waitcnt vmcnt(0)" ::: "memory");
        __builtin_amdgcn_sched_barrier(0);
        AC1(w0) AC1(w1) AC1(w2) AC1(w3) AC1(w4) AC1(w5) AC1(w6) AC1(w7)
    }
    const _Float16* selfrow = (const _Float16*)(hs + (size_t)node * 32 + le16);
    float dv = dinv[node];
    float q0 = dv * (a0 + (float)selfrow[0]), q1 = dv * (a1 + (float)selfrow[1]);
    float q2 = dv * (a2 + (float)selfrow[2]), q3 = dv * (a3 + (float)selfrow[3]);
    float q4 = dv * (a4 + (float)selfrow[4]), q5 = dv * (a5 + (float)selfrow[5]);
    float q6 = dv * (a6 + (float)selfrow[6]), q7 = dv * (a7 + (float)selfrow[7]);
    const float4* b1v = (const float4*)(b1 + le * 8);
    float4 ba = b1v[0], bb = b1v[1];
    const float4* w2v = (const float4*)(W2 + le * 16);
    float4 wA = w2v[0], wB = w2v[1], wC = w2v[2], wD = w2v[3];
    float p0 = 0.f, p1 = 0.f, r;
    r = fmaxf(q0 + ba.x, 0.f); p0 = fmaf(r, wA.x, p0); p1 = fmaf(r, wA.y, p1);
    r = fmaxf(q1 + ba.y, 0.f); p0 = fmaf(r, wA.z, p0); p1 = fmaf(r, wA.w, p1);
    r = fmaxf(q2 + ba.z, 0.f); p0 = fmaf(r, wB.x, p0); p1 = fmaf(r, wB.y, p1);
    r = fmaxf(q3 + ba.w, 0.f); p0 = fmaf(r, wB.z, p0); p1 = fmaf(r, wB.w, p1);
    r = fmaxf(q4 + bb.x, 0.f); p0 = fmaf(r, wC.x, p0); p1 = fmaf(r, wC.y, p1);
    r = fmaxf(q5 + bb.y, 0.f); p0 = fmaf(r, wC.z, p0); p1 = fmaf(r, wC.w, p1);
    r = fmaxf(q6 + bb.z, 0.f); p0 = fmaf(r, wD.x, p0); p1 = fmaf(r, wD.y, p1);
    r = fmaxf(q7 + bb.w, 0.f); p0 = fmaf(r, wD.z, p0); p1 = fmaf(r, wD.w, p1);
    p0 += __shfl_xor(p0, 1);
    p1 += __shfl_xor(p1, 1);
    if (le == 0) {
        float2 h2; h2.x = p0 * dv; h2.y = p1 * dv;
        hs2[node] = h2;
    }
}

// ---------- layer-2 aggregation + finalize ----------
__global__ __launch_bounds__(256) void k_agg2(const unsigned* __restrict__ adj2,
                                              const int* __restrict__ rsA,
                                              const int* __restrict__ reA,
                                              const char* __restrict__ hs2,
                                              const float* __restrict__ dinv,
                                              const float* __restrict__ b2,
                                              float2* __restrict__ out) {
    int node = blockIdx.x * 256 + threadIdx.x;
    if (node >= N_NODES) return;
    int rs0 = rsA[node], re0 = reA[node];
    unsigned dummy_off = DUMMY_E * 8u;

    float a0 = 0.f, a1 = 0.f;
    f32x2 w0, w1, w2, w3, w4, w5, w6, w7;

#define GL2(dst, o) asm volatile("global_load_dwordx2 %0, %1, %2" \
    : "=v"(dst) : "v"(o), "s"(hs2) : "memory");

    for (int bs = rs0; bs < re0; bs += 8) {
        const unsigned* ap = adj2 + bs;
        unsigned j0 = ap[0], j1 = ap[1], j2 = ap[2], j3 = ap[3];
        unsigned j4 = ap[4], j5 = ap[5], j6 = ap[6], j7 = ap[7];
        unsigned o0 = (bs + 0 < re0) ? (j0 << 3) : dummy_off;
        unsigned o1 = (bs + 1 < re0) ? (j1 << 3) : dummy_off;
        unsigned o2 = (bs + 2 < re0) ? (j2 << 3) : dummy_off;
        unsigned o3 = (bs + 3 < re0) ? (j3 << 3) : dummy_off;
        unsigned o4 = (bs + 4 < re0) ? (j4 << 3) : dummy_off;
        unsigned o5 = (bs + 5 < re0) ? (j5 << 3) : dummy_off;
        unsigned o6 = (bs + 6 < re0) ? (j6 << 3) : dummy_off;
        unsigned o7 = (bs + 7 < re0) ? (j7 << 3) : dummy_off;
        GL2(w0, o0) GL2(w1, o1) GL2(w2, o2) GL2(w3, o3)
        GL2(w4, o4) GL2(w5, o5) GL2(w6, o6) GL2(w7, o7)
        asm volatile("s_waitcnt vmcnt(0)" ::: "memory");
        __builtin_amdgcn_sched_barrier(0);
        a0 += w0[0] + w1[0] + w2[0] + w3[0] + w4[0] + w5[0] + w6[0] + w7[0];
        a1 += w0[1] + w1[1] + w2[1] + w3[1] + w4[1] + w5[1] + w6[1] + w7[1];
    }
    const float2* h2p = (const float2*)hs2;
    float2 selfv = h2p[node];
    float dv = dinv[node];
    float2 r;
    r.x = fmaf(dv, a0 + selfv.x, b2[0]);
    r.y = fmaf(dv, a1 + selfv.y, b2[1]);
    out[node] = r;
}

// ---------- launcher ----------
extern "C" void kernel_launch(void* const* d_in, const int* in_sizes, int n_in,
                              void* d_out, int out_size, void* d_ws, size_t ws_size,
                              hipStream_t stream) {
    const float* x   = (const float*)d_in[0];
    const int*   ei  = (const int*)d_in[1];
    const int*   srcv = ei;
    const int*   dstv = ei + N_EDGES;
    const float* W1  = (const float*)d_in[2];
    const float* b1  = (const float*)d_in[3];
    const float* W2  = (const float*)d_in[4];
    const float* b2  = (const float*)d_in[5];
    float* out = (float*)d_out;

    char* w = (char*)d_ws;
    unsigned* adj    = (unsigned*)w;  w += (size_t)NB * CAP * 4;          // 14.4 MB (dead after sortbucket)
    unsigned* adj2   = (unsigned*)w;  w += (size_t)(NB * CAP + 8) * 4;    // 14.4 MB + pad
    unsigned* cursor = (unsigned*)w;  w += (size_t)NB * 4;
    int*      rsA    = (int*)w;       w += (size_t)N_NODES * 4;           // 0.4 MB
    int*      reA    = (int*)w;       w += (size_t)N_NODES * 4;           // 0.4 MB
    float*    dinv   = (float*)w;     w += (size_t)N_NODES * 4;           // 0.4 MB
    // hs / hs2 alias the dead adj region (mm1 runs after sortbucket)
    char*  hs  = (char*)adj;                                              // 3.2 MB fp16
    float* hs2 = (float*)(hs + (size_t)NPAD * HIDDEN * 2);                // 0.8 MB

    k_init       <<<1, 512, 0, stream>>>(cursor);
    k_scatter    <<<G, 256, 0, stream>>>(srcv, dstv, cursor, adj);
    k_sortbucket <<<NB, 256, 0, stream>>>(adj, cursor, adj2, rsA, reA, dinv);
    k_mm1        <<<NPAD / MM1_NODES, 256, 0, stream>>>(x, W1, dinv, (half4*)hs);
    k_agg1       <<<(2 * NPAD) / 256, 256, 0, stream>>>(adj2, rsA, reA, hs, dinv,
                                                        b1, W2, (float2*)hs2);
    k_agg2       <<<(NPAD + 255) / 256, 256, 0, stream>>>(adj2, rsA, reA, (const char*)hs2,
                                                          dinv, b2, (float2*)out);
}

// Round 12
// 125.005 us; speedup vs baseline: 5.1170x; 1.1617x over previous
//
#include <hip/hip_runtime.h>

#define N_NODES 100000
#define N_EDGES 3200000
#define F_IN    128
#define HIDDEN  16
#define F_OUT   2

#define BSZ     256                  // nodes per bucket
#define NB      391                  // ceil(N_NODES / BSZ)
#define NPAD    (NB * BSZ)           // 100096 padded node rows
#define G       800                  // edge-partition blocks for hist/scatter
#define EPB     (N_EDGES / G)        // 4000 edges per partition (exact, even)
#define DUMMY_E 100000u              // zeroed pad row used for clamped slots

typedef float  f32x4 __attribute__((ext_vector_type(4)));
typedef float  f32x2 __attribute__((ext_vector_type(2)));
typedef _Float16 half8 __attribute__((ext_vector_type(8)));
typedef _Float16 half4 __attribute__((ext_vector_type(4)));

// ---------- P1: per-partition bucket histogram (int2 loads, 2 sub-hists) ----------
__global__ __launch_bounds__(256) void k_hist(const int* __restrict__ dst,
                                              unsigned* __restrict__ blockHist) {
    __shared__ unsigned h0[NB];
    __shared__ unsigned h1[NB];
    int t = threadIdx.x, g = blockIdx.x;
    for (int i = t; i < NB; i += 256) { h0[i] = 0u; h1[i] = 0u; }
    __syncthreads();
    const int2* d2 = (const int2*)(dst + g * EPB);
    unsigned* myh = (t & 1) ? h1 : h0;
    for (int i = t; i < EPB / 2; i += 256) {
        int2 v = d2[i];
        atomicAdd(&myh[(unsigned)v.x >> 8], 1u);
        atomicAdd(&myh[(unsigned)v.y >> 8], 1u);
    }
    __syncthreads();
    for (int i = t; i < NB; i += 256) blockHist[i * G + g] = h0[i] + h1[i];
}

// ---------- P2: per-bucket exclusive scan over partitions ----------
__global__ __launch_bounds__(1024) void k_scan_blocks(unsigned* __restrict__ blockHist,
                                                      unsigned* __restrict__ total) {
    __shared__ unsigned s[1024];
    int b = blockIdx.x, t = threadIdx.x;
    unsigned v = (t < G) ? blockHist[b * G + t] : 0u;
    s[t] = v;
    __syncthreads();
    for (int off = 1; off < 1024; off <<= 1) {
        unsigned xv = (t >= off) ? s[t - off] : 0u;
        __syncthreads();
        s[t] += xv;
        __syncthreads();
    }
    if (t < G) blockHist[b * G + t] = s[t] - v;
    if (t == 1023) total[b] = s[t];
}

// ---------- P2c: exclusive scan of bucket totals ----------
__global__ __launch_bounds__(512) void k_scan_buckets(const unsigned* __restrict__ total,
                                                      unsigned* __restrict__ bucketBase,
                                                      int* __restrict__ rowstart) {
    __shared__ unsigned s[512];
    int t = threadIdx.x;
    unsigned v = (t < NB) ? total[t] : 0u;
    s[t] = v;
    __syncthreads();
    for (int off = 1; off < 512; off <<= 1) {
        unsigned xv = (t >= off) ? s[t - off] : 0u;
        __syncthreads();
        s[t] += xv;
        __syncthreads();
    }
    if (t < NB) bucketBase[t] = s[t] - v;
    if (t == 511) {
        bucketBase[NB] = s[t];                 // == N_EDGES
        rowstart[N_NODES] = (int)s[t];
    }
}

// ---------- P3: LDS counting-sort scatter -> bucket-sorted adjacency ----------
// entry: (dst & 255) << 17 | src ; LDS ~31.3 KB -> 5 blocks/CU
__global__ __launch_bounds__(256) void k_scatter(const int* __restrict__ src,
                                                 const int* __restrict__ dst,
                                                 const unsigned* __restrict__ blockHist,
                                                 const unsigned* __restrict__ bucketBase,
                                                 unsigned* __restrict__ adj) {
    __shared__ unsigned stage[EPB];            // 16.0 KB
    __shared__ unsigned short stage_b[EPB];    // 8.0 KB
    __shared__ unsigned hist[NB];              // cursor
    __shared__ unsigned h1[NB];                // sub-hist
    __shared__ unsigned lstart[NB];
    __shared__ unsigned gbase[NB];
    __shared__ unsigned ssum[256];
    int t = threadIdx.x, g = blockIdx.x;
    for (int i = t; i < NB; i += 256) {
        hist[i] = 0u; h1[i] = 0u;
        gbase[i] = bucketBase[i] + blockHist[i * G + g];
    }
    __syncthreads();
    const int2* s2 = (const int2*)(src + g * EPB);
    const int2* d2 = (const int2*)(dst + g * EPB);
    // phase 1: local histogram (2 sub-hists)
    unsigned* myh = (t & 1) ? h1 : hist;
    for (int i = t; i < EPB / 2; i += 256) {
        int2 v = d2[i];
        atomicAdd(&myh[(unsigned)v.x >> 8], 1u);
        atomicAdd(&myh[(unsigned)v.y >> 8], 1u);
    }
    __syncthreads();
    // phase 2: merge + exclusive scan -> lstart; hist becomes cursor
    int i0 = t * 2;
    unsigned v0 = (i0 + 0 < NB) ? hist[i0 + 0] + h1[i0 + 0] : 0u;
    unsigned v1 = (i0 + 1 < NB) ? hist[i0 + 1] + h1[i0 + 1] : 0u;
    unsigned my = v0 + v1;
    ssum[t] = my;
    __syncthreads();
    for (int off = 1; off < 256; off <<= 1) {
        unsigned xv = (t >= off) ? ssum[t - off] : 0u;
        __syncthreads();
        ssum[t] += xv;
        __syncthreads();
    }
    unsigned e0 = ssum[t] - my;
    __syncthreads();
    unsigned e1 = e0 + v0;
    if (i0 + 0 < NB) { lstart[i0 + 0] = e0; hist[i0 + 0] = e0; }
    if (i0 + 1 < NB) { lstart[i0 + 1] = e1; hist[i0 + 1] = e1; }
    __syncthreads();
    // phase 3: stage entries bucket-ordered in LDS
    for (int i = t; i < EPB / 2; i += 256) {
        int2 sv = s2[i], dv = d2[i];
        unsigned bkt0 = (unsigned)dv.x >> 8;
        unsigned pos0 = atomicAdd(&hist[bkt0], 1u);
        stage[pos0] = ((unsigned)(dv.x & 255) << 17) | (unsigned)sv.x;
        stage_b[pos0] = (unsigned short)bkt0;
        unsigned bkt1 = (unsigned)dv.y >> 8;
        unsigned pos1 = atomicAdd(&hist[bkt1], 1u);
        stage[pos1] = ((unsigned)(dv.y & 255) << 17) | (unsigned)sv.y;
        stage_b[pos1] = (unsigned short)bkt1;
    }
    __syncthreads();
    // phase 4: grouped global writes (ascending runs per bucket)
    for (int j = t; j < EPB; j += 256) {
        unsigned bkt = stage_b[j];
        adj[gbase[bkt] + (j - lstart[bkt])] = stage[j];
    }
}

// ---------- P4: in-bucket counting sort -> CSR (adj2 = src only), rowstart, dinv ----------
// 512 threads: histogram & scatter phases use all; 256-bin scan uses t<256.
__global__ __launch_bounds__(512) void k_sortbucket(const unsigned* __restrict__ adj,
                                                    const unsigned* __restrict__ bucketBase,
                                                    unsigned* __restrict__ adj2,
                                                    int* __restrict__ rowstart,
                                                    float* __restrict__ dinv) {
    __shared__ unsigned hist[BSZ];
    __shared__ unsigned sc[BSZ];
    __shared__ unsigned cur[BSZ];
    int b = blockIdx.x, t = threadIdx.x;
    if (t < BSZ) hist[t] = 0u;
    __syncthreads();
    int e0 = (int)bucketBase[b], e1 = (int)bucketBase[b + 1];
    for (int i = e0 + t; i < e1; i += 512) atomicAdd(&hist[adj[i] >> 17], 1u);
    __syncthreads();
    if (t < BSZ) sc[t] = hist[t];
    __syncthreads();
    for (int off = 1; off < BSZ; off <<= 1) {
        unsigned a = 0;
        if (t < BSZ && t >= off) a = sc[t - off];
        __syncthreads();
        if (t < BSZ) sc[t] += a;
        __syncthreads();
    }
    if (t < BSZ) {
        unsigned excl = sc[t] - hist[t];
        cur[t] = (unsigned)e0 + excl;
        int node = b * BSZ + t;
        if (node < N_NODES) {
            rowstart[node] = e0 + (int)excl;
            dinv[node] = rsqrtf((float)(hist[t] + 1u));
        }
    }
    __syncthreads();
    for (int i = e0 + t; i < e1; i += 512) {
        unsigned v = adj[i];
        unsigned pos = atomicAdd(&cur[v >> 17], 1u);
        adj2[pos] = v & 0x1FFFFu;
    }
}

// ---------- layer-1 GEMM: hs(fp16) = (x @ W1) * dinv ----------
#define MM1_NODES 64
#define SXP 132
__global__ __launch_bounds__(256) void k_mm1(const float* __restrict__ x,
                                             const float* __restrict__ W1,
                                             const float* __restrict__ dinv,
                                             half4* __restrict__ hs) {
    __shared__ float sW[F_IN * HIDDEN];       // 8 KB
    __shared__ float sX[MM1_NODES * SXP];     // 33 KB
    int t = threadIdx.x;
    for (int i = t; i < F_IN * HIDDEN; i += 256) sW[i] = W1[i];
    int node0 = blockIdx.x * MM1_NODES;
    const float4* xv = (const float4*)(x + (size_t)node0 * F_IN);
    int maxv = (N_NODES - node0) * (F_IN / 4);
    if (maxv < 0) maxv = 0;
    for (int i = t; i < MM1_NODES * (F_IN / 4); i += 256) {
        if (i < maxv) {
            int nl = i >> 5, f4 = i & 31;
            ((float4*)(sX + nl * SXP))[f4] = xv[i];
        }
    }
    __syncthreads();
    int lane4 = t & 3;
    int nl = t >> 2;
    int n = node0 + nl;
    if (n >= NPAD) return;
    if (n >= N_NODES) {                       // zero pad rows incl. DUMMY row
        half4 hz = {(_Float16)0.f, (_Float16)0.f, (_Float16)0.f, (_Float16)0.f};
        hs[(size_t)n * 4 + lane4] = hz;
        return;
    }
    const float4* sWv = (const float4*)sW;
    float4 a = {0.f, 0.f, 0.f, 0.f};
    #pragma unroll 8
    for (int f = 0; f < F_IN; ++f) {
        float xval = sX[nl * SXP + f];
        float4 w = sWv[f * 4 + lane4];
        a.x = fmaf(xval, w.x, a.x);
        a.y = fmaf(xval, w.y, a.y);
        a.z = fmaf(xval, w.z, a.z);
        a.w = fmaf(xval, w.w, a.w);
    }
    float dv = dinv[n];
    half4 h; h[0] = (_Float16)(a.x * dv); h[1] = (_Float16)(a.y * dv);
    h[2] = (_Float16)(a.z * dv); h[3] = (_Float16)(a.w * dv);
    hs[(size_t)n * 4 + lane4] = h;
}

// ---------- layer-1 aggregation + FUSED layer-2 matmul ----------
// 2 lanes per node; each lane owns 8 fp16 channels; asm-forced 8-deep gathers.
__global__ __launch_bounds__(256) void k_agg1(const unsigned* __restrict__ adj2,
                                              const int* __restrict__ rowstart,
                                              const char* __restrict__ hs,
                                              const float* __restrict__ dinv,
                                              const float* __restrict__ b1,
                                              const float* __restrict__ W2,
                                              float2* __restrict__ hs2) {
    int g = blockIdx.x * 256 + threadIdx.x;
    int node = g >> 1, le = g & 1;
    if (node >= N_NODES) {                     // zero pad rows incl. DUMMY
        if (le == 0 && node < NPAD) { float2 z = {0.f, 0.f}; hs2[node] = z; }
        return;
    }
    int rs = rowstart[node], re = rowstart[node + 1];
    unsigned le16 = (unsigned)le * 16u;
    unsigned dummy_off = DUMMY_E * 32u + le16;

    float a0 = 0.f, a1 = 0.f, a2 = 0.f, a3 = 0.f, a4 = 0.f, a5 = 0.f, a6 = 0.f, a7 = 0.f;
    f32x4 w0, w1, w2, w3, w4, w5, w6, w7;

#define GL1(dst, o) asm volatile("global_load_dwordx4 %0, %1, %2" \
    : "=v"(dst) : "v"(o), "s"(hs) : "memory");
#define AC1(w_) { half8 h8; __builtin_memcpy(&h8, &w_, 16); \
    a0 += (float)h8[0]; a1 += (float)h8[1]; a2 += (float)h8[2]; a3 += (float)h8[3]; \
    a4 += (float)h8[4]; a5 += (float)h8[5]; a6 += (float)h8[6]; a7 += (float)h8[7]; }

    for (int bs = rs; bs < re; bs += 8) {
        const unsigned* ap = adj2 + bs;        // adj2 padded by 8 -> safe reads
        unsigned j0 = ap[0], j1 = ap[1], j2 = ap[2], j3 = ap[3];
        unsigned j4 = ap[4], j5 = ap[5], j6 = ap[6], j7 = ap[7];
        unsigned o0 = (bs + 0 < re) ? (j0 << 5) + le16 : dummy_off;
        unsigned o1 = (bs + 1 < re) ? (j1 << 5) + le16 : dummy_off;
        unsigned o2 = (bs + 2 < re) ? (j2 << 5) + le16 : dummy_off;
        unsigned o3 = (bs + 3 < re) ? (j3 << 5) + le16 : dummy_off;
        unsigned o4 = (bs + 4 < re) ? (j4 << 5) + le16 : dummy_off;
        unsigned o5 = (bs + 5 < re) ? (j5 << 5) + le16 : dummy_off;
        unsigned o6 = (bs + 6 < re) ? (j6 << 5) + le16 : dummy_off;
        unsigned o7 = (bs + 7 < re) ? (j7 << 5) + le16 : dummy_off;
        GL1(w0, o0) GL1(w1, o1) GL1(w2, o2) GL1(w3, o3)
        GL1(w4, o4) GL1(w5, o5) GL1(w6, o6) GL1(w7, o7)
        asm volatile("s_waitcnt vmcnt(0)" ::: "memory");
        __builtin_amdgcn_sched_barrier(0);
        AC1(w0) AC1(w1) AC1(w2) AC1(w3) AC1(w4) AC1(w5) AC1(w6) AC1(w7)
    }
    const _Float16* selfrow = (const _Float16*)(hs + (size_t)node * 32 + le16);
    float dv = dinv[node];
    float q0 = dv * (a0 + (float)selfrow[0]), q1 = dv * (a1 + (float)selfrow[1]);
    float q2 = dv * (a2 + (float)selfrow[2]), q3 = dv * (a3 + (float)selfrow[3]);
    float q4 = dv * (a4 + (float)selfrow[4]), q5 = dv * (a5 + (float)selfrow[5]);
    float q6 = dv * (a6 + (float)selfrow[6]), q7 = dv * (a7 + (float)selfrow[7]);
    const float4* b1v = (const float4*)(b1 + le * 8);
    float4 ba = b1v[0], bb = b1v[1];
    const float4* w2v = (const float4*)(W2 + le * 16);
    float4 wA = w2v[0], wB = w2v[1], wC = w2v[2], wD = w2v[3];
    float p0 = 0.f, p1 = 0.f, r;
    r = fmaxf(q0 + ba.x, 0.f); p0 = fmaf(r, wA.x, p0); p1 = fmaf(r, wA.y, p1);
    r = fmaxf(q1 + ba.y, 0.f); p0 = fmaf(r, wA.z, p0); p1 = fmaf(r, wA.w, p1);
    r = fmaxf(q2 + ba.z, 0.f); p0 = fmaf(r, wB.x, p0); p1 = fmaf(r, wB.y, p1);
    r = fmaxf(q3 + ba.w, 0.f); p0 = fmaf(r, wB.z, p0); p1 = fmaf(r, wB.w, p1);
    r = fmaxf(q4 + bb.x, 0.f); p0 = fmaf(r, wC.x, p0); p1 = fmaf(r, wC.y, p1);
    r = fmaxf(q5 + bb.y, 0.f); p0 = fmaf(r, wC.z, p0); p1 = fmaf(r, wC.w, p1);
    r = fmaxf(q6 + bb.z, 0.f); p0 = fmaf(r, wD.x, p0); p1 = fmaf(r, wD.y, p1);
    r = fmaxf(q7 + bb.w, 0.f); p0 = fmaf(r, wD.z, p0); p1 = fmaf(r, wD.w, p1);
    p0 += __shfl_xor(p0, 1);
    p1 += __shfl_xor(p1, 1);
    if (le == 0) {
        float2 h2; h2.x = p0 * dv; h2.y = p1 * dv;
        hs2[node] = h2;
    }
}

// ---------- layer-2 aggregation + finalize ----------
__global__ __launch_bounds__(256) void k_agg2(const unsigned* __restrict__ adj2,
                                              const int* __restrict__ rowstart,
                                              const char* __restrict__ hs2,
                                              const float* __restrict__ dinv,
                                              const float* __restrict__ b2,
                                              float2* __restrict__ out) {
    int node = blockIdx.x * 256 + threadIdx.x;
    if (node >= N_NODES) return;
    int rs = rowstart[node], re = rowstart[node + 1];
    unsigned dummy_off = DUMMY_E * 8u;

    float a0 = 0.f, a1 = 0.f;
    f32x2 w0, w1, w2, w3, w4, w5, w6, w7;

#define GL2(dst, o) asm volatile("global_load_dwordx2 %0, %1, %2" \
    : "=v"(dst) : "v"(o), "s"(hs2) : "memory");

    for (int bs = rs; bs < re; bs += 8) {
        const unsigned* ap = adj2 + bs;
        unsigned j0 = ap[0], j1 = ap[1], j2 = ap[2], j3 = ap[3];
        unsigned j4 = ap[4], j5 = ap[5], j6 = ap[6], j7 = ap[7];
        unsigned o0 = (bs + 0 < re) ? (j0 << 3) : dummy_off;
        unsigned o1 = (bs + 1 < re) ? (j1 << 3) : dummy_off;
        unsigned o2 = (bs + 2 < re) ? (j2 << 3) : dummy_off;
        unsigned o3 = (bs + 3 < re) ? (j3 << 3) : dummy_off;
        unsigned o4 = (bs + 4 < re) ? (j4 << 3) : dummy_off;
        unsigned o5 = (bs + 5 < re) ? (j5 << 3) : dummy_off;
        unsigned o6 = (bs + 6 < re) ? (j6 << 3) : dummy_off;
        unsigned o7 = (bs + 7 < re) ? (j7 << 3) : dummy_off;
        GL2(w0, o0) GL2(w1, o1) GL2(w2, o2) GL2(w3, o3)
        GL2(w4, o4) GL2(w5, o5) GL2(w6, o6) GL2(w7, o7)
        asm volatile("s_waitcnt vmcnt(0)" ::: "memory");
        __builtin_amdgcn_sched_barrier(0);
        a0 += w0[0] + w1[0] + w2[0] + w3[0] + w4[0] + w5[0] + w6[0] + w7[0];
        a1 += w0[1] + w1[1] + w2[1] + w3[1] + w4[1] + w5[1] + w6[1] + w7[1];
    }
    const float2* h2p = (const float2*)hs2;
    float2 selfv = h2p[node];
    float dv = dinv[node];
    float2 r;
    r.x = fmaf(dv, a0 + selfv.x, b2[0]);
    r.y = fmaf(dv, a1 + selfv.y, b2[1]);
    out[node] = r;
}

// ---------- launcher ----------
extern "C" void kernel_launch(void* const* d_in, const int* in_sizes, int n_in,
                              void* d_out, int out_size, void* d_ws, size_t ws_size,
                              hipStream_t stream) {
    const float* x   = (const float*)d_in[0];
    const int*   ei  = (const int*)d_in[1];
    const int*   srcv = ei;
    const int*   dstv = ei + N_EDGES;
    const float* W1  = (const float*)d_in[2];
    const float* b1  = (const float*)d_in[3];
    const float* W2  = (const float*)d_in[4];
    const float* b2  = (const float*)d_in[5];
    float* out = (float*)d_out;

    char* w = (char*)d_ws;
    unsigned* adj        = (unsigned*)w;  w += (size_t)N_EDGES * 4;        // 12.8 MB
    unsigned* adj2       = (unsigned*)w;  w += (size_t)(N_EDGES + 8) * 4;  // 12.8 MB + pad
    unsigned* blockHist  = (unsigned*)w;  w += (size_t)NB * G * 4;         // 1.25 MB
    unsigned* total      = (unsigned*)w;  w += (size_t)NB * 4;
    unsigned* bucketBase = (unsigned*)w;  w += (size_t)(NB + 1) * 4;
    int*      rowstart   = (int*)w;       w += (size_t)(N_NODES + 1) * 4;  // 0.4 MB
    w = (char*)(((size_t)w + 15) & ~(size_t)15);
    float* dinv  = (float*)w;  w += (size_t)N_NODES * 4;                   // 0.4 MB
    char*  hs    = w;          w += (size_t)NPAD * HIDDEN * 2;             // 3.2 MB fp16
    float* hs2   = (float*)w;                                              // 0.8 MB

    k_hist        <<<G, 256, 0, stream>>>(dstv, blockHist);
    k_scan_blocks <<<NB, 1024, 0, stream>>>(blockHist, total);
    k_scan_buckets<<<1, 512, 0, stream>>>(total, bucketBase, rowstart);
    k_scatter     <<<G, 256, 0, stream>>>(srcv, dstv, blockHist, bucketBase, adj);
    k_sortbucket  <<<NB, 512, 0, stream>>>(adj, bucketBase, adj2, rowstart, dinv);
    k_mm1         <<<NPAD / MM1_NODES, 256, 0, stream>>>(x, W1, dinv, (half4*)hs);
    k_agg1        <<<(2 * NPAD) / 256, 256, 0, stream>>>(adj2, rowstart, hs, dinv,
                                                         b1, W2, (float2*)hs2);
    k_agg2        <<<(NPAD + 255) / 256, 256, 0, stream>>>(adj2, rowstart, (const char*)hs2,
                                                           dinv, b2, (float2*)out);
}